// Round 20
// baseline (18.324 us; speedup 1.0000x reference)
//
#include <hip/hip_runtime.h>
#include <math.h>

namespace {
constexpr int L = 512, S = 512, H = 8, D = 64, K64 = 64;
constexpr float LOG2E = 1.4426950408889634f;
constexpr int SCW = 40;              // w-scratch stride (elems): 80 B -> 16B-aligned b128 reads

typedef __bf16 bf16x8 __attribute__((ext_vector_type(8)));
typedef __bf16 bf16x4 __attribute__((ext_vector_type(4)));
typedef float  f32x4  __attribute__((ext_vector_type(4)));

__device__ inline f32x4 mfma16(bf16x8 a, bf16x8 b, f32x4 c) {
    return __builtin_amdgcn_mfma_f32_16x16x32_bf16(a, b, c, 0, 0, 0);
}
__device__ inline bf16x8 tobf8(f32x4 a, f32x4 b) {
    bf16x8 r;
    r[0] = (__bf16)a[0]; r[1] = (__bf16)a[1];
    r[2] = (__bf16)a[2]; r[3] = (__bf16)a[3];
    r[4] = (__bf16)b[0]; r[5] = (__bf16)b[1];
    r[6] = (__bf16)b[2]; r[7] = (__bf16)b[3];
    return r;
}

// Single dispatch. grid 256 = XCD-swizzled nh(16) x mt(8) x dt(2); 512 thr = 8 waves.
// Wave wv: lw = wv&3 -> 16 l-rows (l0w = mt*64+lw*16); dh = wv>>2 -> 16 d-cols.
// LDS:
//   vf  [32 st][2 kh][64 lane] bf16x8 = 64 KB   v fragments (w-GEMM A-operand)
//   lB  [2 pl][2 cg][16 ks][64 lane] bf16x8 = 64 KB  feature planes {(K+kl)*V, K+kl}
//   wscr[8 wv][2][16*SCW] bf16 = 20 KB          per-wave double scratch (w tiles)
// Main loop (per wave, barrier-free), per ks:
//   wT = mfma(vf, u)  -> lane r holds w[l=r][s=st*16+kg*4+reg]  (s lane-local)
//   + mask (ONE f32x4/half) -> ONE ds_write_b64/half -> b128 a-frag read
//   -> accn += mfma(a, lB_N), accd += mfma(a, lB_D).
// R20 = R19 with unroll depth 2 (deconfound: R19's only other change vs R18
// was full unroll, suspected VGPR-spill regressor).
__global__ __launch_bounds__(512, 1) void aft_once(
    const float* __restrict__ u, const float* __restrict__ v,
    const float* __restrict__ mask, const float* __restrict__ keys,
    const float* __restrict__ values, const float* __restrict__ klen,
    const float* __restrict__ queries, float* __restrict__ out)
{
    __shared__ bf16x8 vf[4096];           // 64 KB
    __shared__ bf16x8 lB[4096];           // 64 KB
    __shared__ __bf16 wscr[8][2][16 * SCW];  // 20 KB
    __shared__ float  svred[32][17];      // 2.2 KB
    __shared__ float  svl[32];

    const int b = blockIdx.x;
    const int xcd = b & 7;
    const int i = b >> 3;                  // 0..31
    const int nh = xcd + ((i >> 4) << 3);  // {xcd, xcd+8}
    const int rem = i & 15;
    const int mt = rem >> 1;               // 0..7 (64 l-rows)
    const int dt = rem & 1;                // 0..1 (32 d-cols)
    const int n = nh >> 3, h = nh & 7;

    const int t = threadIdx.x;
    const int wv = t >> 6;
    const int lane = t & 63;
    const int r = lane & 15;
    const int kg = lane >> 4;
    const int lw = wv & 3;
    const int dh = wv >> 2;
    const int l0w = mt * 64 + lw * 16;

    // ---- stage v -> LDS fragments (coalesced rows; unit = st*128+kh*64+kg*16+r) ----
    {
        const int rq = t >> 4;             // 0..31
        const int c4 = (t & 15) << 2;      // 0..60
        const int kh = c4 >> 5, kgv = (c4 >> 3) & 3, e0 = c4 & 7;
        __bf16* vfE = (__bf16*)vf;
        #pragma unroll
        for (int rd = 0; rd < 16; ++rd) {
            const int row = rq + rd * 32;
            const f32x4 v4 = *(const f32x4*)(v + (size_t)row * K64 + c4);
            bf16x4 p;
            p[0] = (__bf16)v4[0]; p[1] = (__bf16)v4[1];
            p[2] = (__bf16)v4[2]; p[3] = (__bf16)v4[3];
            const int unit = ((row >> 4) * 128) + (kh * 64) + (kgv * 16) + (row & 15);
            *(bf16x4*)(vfE + unit * 8 + e0) = p;
        }
    }

    // ---- stage K/V feature planes in fragment layout + SV partials ----
    {
        const int dl = t & 31;             // local d
        const int sg0 = t >> 5;            // 0..15
        const int cg = dl >> 4, rb = dl & 15;
        float sum = 0.f;
        #pragma unroll
        for (int blk = 0; blk < 4; ++blk) {
            const int sgg = sg0 + (blk << 4);   // 0..63 (8-s groups)
            const int ksb = sgg >> 2, kgb = sgg & 3;
            bf16x8 nv, dv;
            #pragma unroll
            for (int j = 0; j < 8; ++j) {
                const int s = sgg * 8 + j;
                const float kl = klen[n * S + s];
                const size_t gi = (((size_t)n * S + s) * H + h) * D + dt * 32 + dl;
                const float kk = keys[gi] + kl;
                const float vv = values[gi];
                nv[j] = (__bf16)(kk * vv);
                dv[j] = (__bf16)kk;
                sum += vv;
            }
            lB[((0 * 2 + cg) * 16 + ksb) * 64 + kgb * 16 + rb] = nv;
            lB[((1 * 2 + cg) * 16 + ksb) * 64 + kgb * 16 + rb] = dv;
        }
        svred[dl][sg0] = sum;
    }

    // ---- early epilogue loads (input-only) ----
    const int dcol = dt * 32 + dh * 16 + r;
    float qv[4];
    size_t qidx[4];
    #pragma unroll
    for (int rr = 0; rr < 4; ++rr) {
        const int l = l0w + kg * 4 + rr;
        qidx[rr] = (((size_t)n * L + l) * H + h) * D + dcol;
        qv[rr] = queries[qidx[rr]];
    }

    // ---- u fragments (w-GEMM B-operand): lane r = l-col, kg = k-octet ----
    const float* urow = u + (size_t)(l0w + r) * K64 + kg * 8;
    const bf16x8 u0 = tobf8(*(const f32x4*)urow, *(const f32x4*)(urow + 4));
    const bf16x8 u1 = tobf8(*(const f32x4*)(urow + 32), *(const f32x4*)(urow + 36));

    __syncthreads();
    if (t < 32) {
        float ssum = 0.f;
        #pragma unroll
        for (int j = 0; j < 16; ++j) ssum += svred[t][j];
        svl[t] = ssum;
    }
    __syncthreads();

    // mask row for this lane: w[l = l0w + r][s] -> mask[(l0w+r)][...]
    const float* mrow = mask + (size_t)(l0w + r) * S;

    f32x4 accn = {0.f, 0.f, 0.f, 0.f};
    f32x4 accd = {0.f, 0.f, 0.f, 0.f};
    __bf16* const scr0 = &wscr[wv][0][0];
    __bf16* const scr1 = &wscr[wv][1][0];

    #pragma unroll 2
    for (int ks = 0; ks < 16; ++ks) {
        __bf16* const scr = (ks & 1) ? scr1 : scr0;
        #pragma unroll
        for (int half = 0; half < 2; ++half) {
            const int st = ks * 2 + half;
            const bf16x8 vf0 = vf[st * 128 + lane];
            const bf16x8 vf1 = vf[st * 128 + 64 + lane];
            // wT = v.uT : lane (r,kg) gets w[l=l0w+r][s=st*16+kg*4+reg]
            f32x4 wacc = {0.f, 0.f, 0.f, 0.f};
            wacc = mfma16(vf0, u0, wacc);
            wacc = mfma16(vf1, u1, wacc);
            const f32x4 m4 = *(const f32x4*)(mrow + st * 16 + kg * 4);
            bf16x4 pk;
            pk[0] = (__bf16)(wacc[0] + m4[0]);
            pk[1] = (__bf16)(wacc[1] + m4[1]);
            pk[2] = (__bf16)(wacc[2] + m4[2]);
            pk[3] = (__bf16)(wacc[3] + m4[3]);
            // elem index = r*SCW + s32 (s32 = half*16 + kg*4 + reg) -> one b64
            *(bf16x4*)(scr + r * SCW + half * 16 + kg * 4) = pk;
        }
        // a-frag: lane (r,kg) reads w[l=r][s32 = kg*8 .. kg*8+7] -> b128
        const bf16x8 a  = *(const bf16x8*)(scr + r * SCW + kg * 8);
        const bf16x8 bn = lB[((0 * 2 + dh) * 16 + ks) * 64 + lane];
        const bf16x8 bd = lB[((1 * 2 + dh) * 16 + ks) * 64 + lane];
        accn = mfma16(a, bn, accn);
        accd = mfma16(a, bd, accd);
    }

    const float sv = svl[dh * 16 + r];
    #pragma unroll
    for (int rr = 0; rr < 4; ++rr) {
        const float sig =
            __builtin_amdgcn_rcpf(1.0f + __builtin_amdgcn_exp2f(-qv[rr] * LOG2E));
        const float numv = sv + accn[rr];
        const float denv = 512.0f + accd[rr];
        out[qidx[rr]] = sig * numv * __builtin_amdgcn_rcpf(denv);
    }
}
} // namespace

extern "C" void kernel_launch(void* const* d_in, const int* in_sizes, int n_in,
                              void* d_out, int out_size, void* d_ws, size_t ws_size,
                              hipStream_t stream)
{
    const float* queries = (const float*)d_in[0];
    const float* keys    = (const float*)d_in[1];
    const float* values  = (const float*)d_in[2];
    const float* mask    = (const float*)d_in[3];
    const float* klen    = (const float*)d_in[4];
    const float* u       = (const float*)d_in[5];
    const float* v       = (const float*)d_in[6];
    float* out = (float*)d_out;

    aft_once<<<dim3(256), dim3(512), 0, stream>>>(
        u, v, mask, keys, values, klen, queries, out);
}

// Round 21
// 15.807 us; speedup vs baseline: 1.1593x; 1.1593x over previous
//
#include <hip/hip_runtime.h>
#include <math.h>

namespace {
constexpr int L = 512, S = 512, H = 8, D = 64, K64 = 64;
constexpr float LOG2E = 1.4426950408889634f;
constexpr int SCW = 40;              // w-scratch stride (elems): 80 B -> 16B-aligned b128 reads

typedef __bf16 bf16x8 __attribute__((ext_vector_type(8)));
typedef __bf16 bf16x4 __attribute__((ext_vector_type(4)));
typedef float  f32x4  __attribute__((ext_vector_type(4)));

__device__ inline f32x4 mfma16(bf16x8 a, bf16x8 b, f32x4 c) {
    return __builtin_amdgcn_mfma_f32_16x16x32_bf16(a, b, c, 0, 0, 0);
}
__device__ inline bf16x8 tobf8(f32x4 a, f32x4 b) {
    bf16x8 r;
    r[0] = (__bf16)a[0]; r[1] = (__bf16)a[1];
    r[2] = (__bf16)a[2]; r[3] = (__bf16)a[3];
    r[4] = (__bf16)b[0]; r[5] = (__bf16)b[1];
    r[6] = (__bf16)b[2]; r[7] = (__bf16)b[3];
    return r;
}

// Single dispatch. grid 256 = XCD-swizzled nh(16) x mt(8) x dt(2); 512 thr = 8 waves.
// Main loop = R18 verbatim (best: 15.73 us): w = mfma(u, vf) + mask,
// scalar b16 scratch writes, b128 a-frag read, unroll 2.
// NEW vs R18: lB staging vectorized — thread (dl4 = t&7, sgg = t>>3) loads
// 8 s x f32x4 over d for K and V (coalesced, 16-deep MLP) + 2 f32x4 klen
// loads, in-register transpose to 4 bf16x8 fragment units per plane.
__global__ __launch_bounds__(512, 1) void aft_once(
    const float* __restrict__ u, const float* __restrict__ v,
    const float* __restrict__ mask, const float* __restrict__ keys,
    const float* __restrict__ values, const float* __restrict__ klen,
    const float* __restrict__ queries, float* __restrict__ out)
{
    __shared__ bf16x8 vf[4096];           // 64 KB
    __shared__ bf16x8 lB[4096];           // 64 KB
    __shared__ __bf16 wscr[8][2][16 * SCW];  // 20 KB
    __shared__ float  svred[64][33];      // 8.25 KB  [sgg][d-local]
    __shared__ float  svl[32];

    const int b = blockIdx.x;
    const int xcd = b & 7;
    const int i = b >> 3;                  // 0..31
    const int nh = xcd + ((i >> 4) << 3);  // {xcd, xcd+8}
    const int rem = i & 15;
    const int mt = rem >> 1;               // 0..7 (64 l-rows)
    const int dt = rem & 1;                // 0..1 (32 d-cols)
    const int n = nh >> 3, h = nh & 7;

    const int t = threadIdx.x;
    const int wv = t >> 6;
    const int lane = t & 63;
    const int r = lane & 15;
    const int kg = lane >> 4;
    const int lw = wv & 3;
    const int dh = wv >> 2;
    const int l0w = mt * 64 + lw * 16;

    // ---- stage v -> LDS fragments (coalesced rows; unit = st*128+kh*64+kg*16+r) ----
    {
        const int rq = t >> 4;             // 0..31
        const int c4 = (t & 15) << 2;      // 0..60
        const int kh = c4 >> 5, kgv = (c4 >> 3) & 3, e0 = c4 & 7;
        __bf16* vfE = (__bf16*)vf;
        #pragma unroll
        for (int rd = 0; rd < 16; ++rd) {
            const int row = rq + rd * 32;
            const f32x4 v4 = *(const f32x4*)(v + (size_t)row * K64 + c4);
            bf16x4 p;
            p[0] = (__bf16)v4[0]; p[1] = (__bf16)v4[1];
            p[2] = (__bf16)v4[2]; p[3] = (__bf16)v4[3];
            const int unit = ((row >> 4) * 128) + (kh * 64) + (kgv * 16) + (row & 15);
            *(bf16x4*)(vfE + unit * 8 + e0) = p;
        }
    }

    // ---- stage K/V feature planes (VECTORIZED) + SV partials ----
    {
        const int dl4 = t & 7;             // 4-d group: d-local = dl4*4 + jd
        const int sgg = t >> 3;            // 0..63 (8-s fragment octet)
        const int ksb = sgg >> 2, kgb = sgg & 3;
        const size_t gbase = (((size_t)n * S + sgg * 8) * H + h) * D + dt * 32 + dl4 * 4;
        const size_t sstep = (size_t)H * D;

        f32x4 K4[8], V4[8];
        #pragma unroll
        for (int j = 0; j < 8; ++j) {
            K4[j] = *(const f32x4*)(keys + gbase + j * sstep);
            V4[j] = *(const f32x4*)(values + gbase + j * sstep);
        }
        const f32x4 kla = *(const f32x4*)(klen + n * S + sgg * 8);
        const f32x4 klb = *(const f32x4*)(klen + n * S + sgg * 8 + 4);
        float kl[8] = {kla[0], kla[1], kla[2], kla[3],
                       klb[0], klb[1], klb[2], klb[3]};

        float sva[4] = {0.f, 0.f, 0.f, 0.f};
        #pragma unroll
        for (int jd = 0; jd < 4; ++jd) {
            bf16x8 nv, dv;
            #pragma unroll
            for (int j = 0; j < 8; ++j) {
                const float kk = K4[j][jd] + kl[j];
                nv[j] = (__bf16)(kk * V4[j][jd]);
                dv[j] = (__bf16)kk;
                sva[jd] += V4[j][jd];
            }
            const int dloc = dl4 * 4 + jd;
            const int cg = dloc >> 4, rb = dloc & 15;
            lB[((0 * 2 + cg) * 16 + ksb) * 64 + kgb * 16 + rb] = nv;
            lB[((1 * 2 + cg) * 16 + ksb) * 64 + kgb * 16 + rb] = dv;
        }
        #pragma unroll
        for (int jd = 0; jd < 4; ++jd) svred[sgg][dl4 * 4 + jd] = sva[jd];
    }

    // ---- early epilogue loads (input-only) ----
    const int dcol = dt * 32 + dh * 16 + r;
    float qv[4];
    size_t qidx[4];
    #pragma unroll
    for (int rr = 0; rr < 4; ++rr) {
        const int l = l0w + kg * 4 + rr;
        qidx[rr] = (((size_t)n * L + l) * H + h) * D + dcol;
        qv[rr] = queries[qidx[rr]];
    }

    // ---- u fragments (w-GEMM A-operand): lane r = l-row, kg = k-octet ----
    const float* urow = u + (size_t)(l0w + r) * K64 + kg * 8;
    const bf16x8 u0 = tobf8(*(const f32x4*)urow, *(const f32x4*)(urow + 4));
    const bf16x8 u1 = tobf8(*(const f32x4*)(urow + 32), *(const f32x4*)(urow + 36));

    __syncthreads();
    if (t < 32) {
        float ssum = 0.f;
        #pragma unroll
        for (int j = 0; j < 64; ++j) ssum += svred[j][t];
        svl[t] = ssum;
    }
    __syncthreads();

    // mask base for C/D rows (row = kg*4 + reg, col = st*16 + r)
    const float* mbase = mask + (size_t)(l0w + kg * 4) * S + r;

    f32x4 accn = {0.f, 0.f, 0.f, 0.f};
    f32x4 accd = {0.f, 0.f, 0.f, 0.f};
    __bf16* const scr0 = &wscr[wv][0][0];
    __bf16* const scr1 = &wscr[wv][1][0];

    #pragma unroll 2
    for (int ks = 0; ks < 16; ++ks) {
        __bf16* const scr = (ks & 1) ? scr1 : scr0;
        #pragma unroll
        for (int half = 0; half < 2; ++half) {
            const int st = ks * 2 + half;
            const bf16x8 vf0 = vf[st * 128 + lane];
            const bf16x8 vf1 = vf[st * 128 + 64 + lane];
            f32x4 wacc = {0.f, 0.f, 0.f, 0.f};
            wacc = mfma16(u0, vf0, wacc);
            wacc = mfma16(u1, vf1, wacc);
            const int colb = half * 16 + r;
            #pragma unroll
            for (int reg = 0; reg < 4; ++reg) {
                const float wt = wacc[reg] + mbase[(size_t)reg * S + st * 16];
                scr[(kg * 4 + reg) * SCW + colb] = (__bf16)wt;
            }
        }
        const bf16x8 a  = *(const bf16x8*)(scr + r * SCW + kg * 8);
        const bf16x8 bn = lB[((0 * 2 + dh) * 16 + ks) * 64 + lane];
        const bf16x8 bd = lB[((1 * 2 + dh) * 16 + ks) * 64 + lane];
        accn = mfma16(a, bn, accn);
        accd = mfma16(a, bd, accd);
    }

    const float sv = svl[dh * 16 + r];
    #pragma unroll
    for (int rr = 0; rr < 4; ++rr) {
        const float sig =
            __builtin_amdgcn_rcpf(1.0f + __builtin_amdgcn_exp2f(-qv[rr] * LOG2E));
        const float numv = sv + accn[rr];
        const float denv = 512.0f + accd[rr];
        out[qidx[rr]] = sig * numv * __builtin_amdgcn_rcpf(denv);
    }
}
} // namespace

extern "C" void kernel_launch(void* const* d_in, const int* in_sizes, int n_in,
                              void* d_out, int out_size, void* d_ws, size_t ws_size,
                              hipStream_t stream)
{
    const float* queries = (const float*)d_in[0];
    const float* keys    = (const float*)d_in[1];
    const float* values  = (const float*)d_in[2];
    const float* mask    = (const float*)d_in[3];
    const float* klen    = (const float*)d_in[4];
    const float* u       = (const float*)d_in[5];
    const float* v       = (const float*)d_in[6];
    float* out = (float*)d_out;

    aft_once<<<dim3(256), dim3(512), 0, stream>>>(
        u, v, mask, keys, values, klen, queries, out);
}

// Round 22
// 15.487 us; speedup vs baseline: 1.1832x; 1.0206x over previous
//
#include <hip/hip_runtime.h>
#include <math.h>

namespace {
constexpr int L = 512, S = 512, H = 8, D = 64, K64 = 64;
constexpr float LOG2E = 1.4426950408889634f;
constexpr int SCW = 40;              // w-scratch stride (elems): 80 B -> 16B-aligned b128 reads

typedef __bf16 bf16x8 __attribute__((ext_vector_type(8)));
typedef __bf16 bf16x4 __attribute__((ext_vector_type(4)));
typedef float  f32x4  __attribute__((ext_vector_type(4)));

__device__ inline f32x4 mfma16(bf16x8 a, bf16x8 b, f32x4 c) {
    return __builtin_amdgcn_mfma_f32_16x16x32_bf16(a, b, c, 0, 0, 0);
}
__device__ inline bf16x8 tobf8(f32x4 a, f32x4 b) {
    bf16x8 r;
    r[0] = (__bf16)a[0]; r[1] = (__bf16)a[1];
    r[2] = (__bf16)a[2]; r[3] = (__bf16)a[3];
    r[4] = (__bf16)b[0]; r[5] = (__bf16)b[1];
    r[6] = (__bf16)b[2]; r[7] = (__bf16)b[3];
    return r;
}

// Single dispatch. grid 256 = XCD-swizzled nh(16) x mt(8) x dt(2); 512 thr = 8 waves.
// Wave wv: lw = wv&3 -> 16 l-rows; dh = wv>>2 -> 16 d-cols.
// NEW vs R21: the (lw,0)/(lw,1) wave pair no longer duplicates the w-GEMM.
// Wave dh produces half st = 2ks+dh of the shared per-lw scratch tile
// (columns s32 in [16dh,16dh+16)); one __syncthreads per ks; both waves
// consume the full 16x32 tile. vf reads/w-MFMAs/mask loads/scratch writes
// per wave halved. Double-buffered on ks&1 (read-vs-rewrite hazard covered
// by the lgkmcnt(0) the compiler emits before each s_barrier).
__global__ __launch_bounds__(512, 1) void aft_once(
    const float* __restrict__ u, const float* __restrict__ v,
    const float* __restrict__ mask, const float* __restrict__ keys,
    const float* __restrict__ values, const float* __restrict__ klen,
    const float* __restrict__ queries, float* __restrict__ out)
{
    __shared__ bf16x8 vf[4096];           // 64 KB
    __shared__ bf16x8 lB[4096];           // 64 KB
    __shared__ __bf16 wscr[4][2][16 * SCW];  // 10 KB  per-lw shared dbl scratch
    __shared__ float  svred[64][33];      // 8.25 KB  [sgg][d-local]
    __shared__ float  svl[32];

    const int b = blockIdx.x;
    const int xcd = b & 7;
    const int i = b >> 3;                  // 0..31
    const int nh = xcd + ((i >> 4) << 3);  // {xcd, xcd+8}
    const int rem = i & 15;
    const int mt = rem >> 1;               // 0..7 (64 l-rows)
    const int dt = rem & 1;                // 0..1 (32 d-cols)
    const int n = nh >> 3, h = nh & 7;

    const int t = threadIdx.x;
    const int wv = t >> 6;
    const int lane = t & 63;
    const int r = lane & 15;
    const int kg = lane >> 4;
    const int lw = wv & 3;
    const int dh = wv >> 2;
    const int l0w = mt * 64 + lw * 16;

    // ---- stage v -> LDS fragments (coalesced rows; unit = st*128+kh*64+kg*16+r) ----
    {
        const int rq = t >> 4;             // 0..31
        const int c4 = (t & 15) << 2;      // 0..60
        const int kh = c4 >> 5, kgv = (c4 >> 3) & 3, e0 = c4 & 7;
        __bf16* vfE = (__bf16*)vf;
        #pragma unroll
        for (int rd = 0; rd < 16; ++rd) {
            const int row = rq + rd * 32;
            const f32x4 v4 = *(const f32x4*)(v + (size_t)row * K64 + c4);
            bf16x4 p;
            p[0] = (__bf16)v4[0]; p[1] = (__bf16)v4[1];
            p[2] = (__bf16)v4[2]; p[3] = (__bf16)v4[3];
            const int unit = ((row >> 4) * 128) + (kh * 64) + (kgv * 16) + (row & 15);
            *(bf16x4*)(vfE + unit * 8 + e0) = p;
        }
    }

    // ---- stage K/V feature planes (vectorized) + SV partials ----
    {
        const int dl4 = t & 7;             // 4-d group: d-local = dl4*4 + jd
        const int sgg = t >> 3;            // 0..63 (8-s fragment octet)
        const int ksb = sgg >> 2, kgb = sgg & 3;
        const size_t gbase = (((size_t)n * S + sgg * 8) * H + h) * D + dt * 32 + dl4 * 4;
        const size_t sstep = (size_t)H * D;

        f32x4 K4[8], V4[8];
        #pragma unroll
        for (int j = 0; j < 8; ++j) {
            K4[j] = *(const f32x4*)(keys + gbase + j * sstep);
            V4[j] = *(const f32x4*)(values + gbase + j * sstep);
        }
        const f32x4 kla = *(const f32x4*)(klen + n * S + sgg * 8);
        const f32x4 klb = *(const f32x4*)(klen + n * S + sgg * 8 + 4);
        float kl[8] = {kla[0], kla[1], kla[2], kla[3],
                       klb[0], klb[1], klb[2], klb[3]};

        float sva[4] = {0.f, 0.f, 0.f, 0.f};
        #pragma unroll
        for (int jd = 0; jd < 4; ++jd) {
            bf16x8 nv, dv;
            #pragma unroll
            for (int j = 0; j < 8; ++j) {
                const float kk = K4[j][jd] + kl[j];
                nv[j] = (__bf16)(kk * V4[j][jd]);
                dv[j] = (__bf16)kk;
                sva[jd] += V4[j][jd];
            }
            const int dloc = dl4 * 4 + jd;
            const int cg = dloc >> 4, rb = dloc & 15;
            lB[((0 * 2 + cg) * 16 + ksb) * 64 + kgb * 16 + rb] = nv;
            lB[((1 * 2 + cg) * 16 + ksb) * 64 + kgb * 16 + rb] = dv;
        }
        #pragma unroll
        for (int jd = 0; jd < 4; ++jd) svred[sgg][dl4 * 4 + jd] = sva[jd];
    }

    // ---- early epilogue loads (input-only) ----
    const int dcol = dt * 32 + dh * 16 + r;
    float qv[4];
    size_t qidx[4];
    #pragma unroll
    for (int rr = 0; rr < 4; ++rr) {
        const int l = l0w + kg * 4 + rr;
        qidx[rr] = (((size_t)n * L + l) * H + h) * D + dcol;
        qv[rr] = queries[qidx[rr]];
    }

    // ---- u fragments (w-GEMM A-operand): lane r = l-row, kg = k-octet ----
    const float* urow = u + (size_t)(l0w + r) * K64 + kg * 8;
    const bf16x8 u0 = tobf8(*(const f32x4*)urow, *(const f32x4*)(urow + 4));
    const bf16x8 u1 = tobf8(*(const f32x4*)(urow + 32), *(const f32x4*)(urow + 36));

    __syncthreads();
    if (t < 32) {
        float ssum = 0.f;
        #pragma unroll
        for (int j = 0; j < 64; ++j) ssum += svred[j][t];
        svl[t] = ssum;
    }
    __syncthreads();

    // mask base for this wave's C/D rows (row = kg*4 + reg, col = st*16 + r)
    const float* mbase = mask + (size_t)(l0w + kg * 4) * S + r;

    f32x4 accn = {0.f, 0.f, 0.f, 0.f};
    f32x4 accd = {0.f, 0.f, 0.f, 0.f};

    #pragma unroll 2
    for (int ks = 0; ks < 16; ++ks) {
        __bf16* const scr = &wscr[lw][ks & 1][0];
        // this wave produces half st = 2ks + dh (columns s32 in [16dh,16dh+16))
        {
            const int st = ks * 2 + dh;
            const bf16x8 vf0 = vf[st * 128 + lane];
            const bf16x8 vf1 = vf[st * 128 + 64 + lane];
            f32x4 wacc = {0.f, 0.f, 0.f, 0.f};
            wacc = mfma16(u0, vf0, wacc);
            wacc = mfma16(u1, vf1, wacc);
            const int colb = dh * 16 + r;
            #pragma unroll
            for (int reg = 0; reg < 4; ++reg) {
                const float wt = wacc[reg] + mbase[(size_t)reg * S + st * 16];
                scr[(kg * 4 + reg) * SCW + colb] = (__bf16)wt;
            }
        }
        __syncthreads();
        const bf16x8 a  = *(const bf16x8*)(scr + r * SCW + kg * 8);
        const bf16x8 bn = lB[((0 * 2 + dh) * 16 + ks) * 64 + lane];
        const bf16x8 bd = lB[((1 * 2 + dh) * 16 + ks) * 64 + lane];
        accn = mfma16(a, bn, accn);
        accd = mfma16(a, bd, accd);
    }

    const float sv = svl[dh * 16 + r];
    #pragma unroll
    for (int rr = 0; rr < 4; ++rr) {
        const float sig =
            __builtin_amdgcn_rcpf(1.0f + __builtin_amdgcn_exp2f(-qv[rr] * LOG2E));
        const float numv = sv + accn[rr];
        const float denv = 512.0f + accd[rr];
        out[qidx[rr]] = sig * numv * __builtin_amdgcn_rcpf(denv);
    }
}
} // namespace

extern "C" void kernel_launch(void* const* d_in, const int* in_sizes, int n_in,
                              void* d_out, int out_size, void* d_ws, size_t ws_size,
                              hipStream_t stream)
{
    const float* queries = (const float*)d_in[0];
    const float* keys    = (const float*)d_in[1];
    const float* values  = (const float*)d_in[2];
    const float* mask    = (const float*)d_in[3];
    const float* klen    = (const float*)d_in[4];
    const float* u       = (const float*)d_in[5];
    const float* v       = (const float*)d_in[6];
    float* out = (float*)d_out;

    aft_once<<<dim3(256), dim3(512), 0, stream>>>(
        u, v, mask, keys, values, klen, queries, out);
}

// Round 23
// 15.180 us; speedup vs baseline: 1.2071x; 1.0202x over previous
//
#include <hip/hip_runtime.h>
#include <math.h>

namespace {
constexpr int L = 512, S = 512, H = 8, D = 64, K64 = 64;
constexpr float LOG2E = 1.4426950408889634f;
constexpr int SCW = 40;              // w-scratch stride (elems): 80 B -> 16B-aligned b128 reads

typedef __bf16 bf16x8 __attribute__((ext_vector_type(8)));
typedef __bf16 bf16x4 __attribute__((ext_vector_type(4)));
typedef float  f32x4  __attribute__((ext_vector_type(4)));

__device__ inline f32x4 mfma16(bf16x8 a, bf16x8 b, f32x4 c) {
    return __builtin_amdgcn_mfma_f32_16x16x32_bf16(a, b, c, 0, 0, 0);
}
__device__ inline bf16x8 tobf8(f32x4 a, f32x4 b) {
    bf16x8 r;
    r[0] = (__bf16)a[0]; r[1] = (__bf16)a[1];
    r[2] = (__bf16)a[2]; r[3] = (__bf16)a[3];
    r[4] = (__bf16)b[0]; r[5] = (__bf16)b[1];
    r[6] = (__bf16)b[2]; r[7] = (__bf16)b[3];
    return r;
}

// Single dispatch. grid 256 = XCD-swizzled nh(16) x mt(8) x dt(2); 512 thr = 8 waves.
// Wave wv: lw = wv&3 -> 16 l-rows; dh = wv>>2 -> 16 d-cols. Wave pair (lw,0/1)
// splits w-production (R22). NEW vs R22: software-pipelined main loop —
// iteration ks issues consume(ks) LDS reads first, then produce(ks+1) into the
// other buffer using a mask value prefetched one iteration earlier (produce
// path has no VMEM wait), then the main MFMAs, then ONE barrier. Double
// buffer: consume reads buf[ks&1], produce writes buf[(ks+1)&1]; rewrite of
// buf[ks&1] happens after the barrier retiring iter-ks reads.
__global__ __launch_bounds__(512, 1) void aft_once(
    const float* __restrict__ u, const float* __restrict__ v,
    const float* __restrict__ mask, const float* __restrict__ keys,
    const float* __restrict__ values, const float* __restrict__ klen,
    const float* __restrict__ queries, float* __restrict__ out)
{
    __shared__ bf16x8 vf[4096];           // 64 KB
    __shared__ bf16x8 lB[4096];           // 64 KB
    __shared__ __bf16 wscr[4][2][16 * SCW];  // 10 KB  per-lw shared dbl scratch
    __shared__ float  svred[64][33];      // 8.25 KB  [sgg][d-local]
    __shared__ float  svl[32];

    const int b = blockIdx.x;
    const int xcd = b & 7;
    const int i = b >> 3;                  // 0..31
    const int nh = xcd + ((i >> 4) << 3);  // {xcd, xcd+8}
    const int rem = i & 15;
    const int mt = rem >> 1;               // 0..7 (64 l-rows)
    const int dt = rem & 1;                // 0..1 (32 d-cols)
    const int n = nh >> 3, h = nh & 7;

    const int t = threadIdx.x;
    const int wv = t >> 6;
    const int lane = t & 63;
    const int r = lane & 15;
    const int kg = lane >> 4;
    const int lw = wv & 3;
    const int dh = wv >> 2;
    const int l0w = mt * 64 + lw * 16;

    // ---- stage v -> LDS fragments (coalesced rows; unit = st*128+kh*64+kg*16+r) ----
    {
        const int rq = t >> 4;             // 0..31
        const int c4 = (t & 15) << 2;      // 0..60
        const int kh = c4 >> 5, kgv = (c4 >> 3) & 3, e0 = c4 & 7;
        __bf16* vfE = (__bf16*)vf;
        #pragma unroll
        for (int rd = 0; rd < 16; ++rd) {
            const int row = rq + rd * 32;
            const f32x4 v4 = *(const f32x4*)(v + (size_t)row * K64 + c4);
            bf16x4 p;
            p[0] = (__bf16)v4[0]; p[1] = (__bf16)v4[1];
            p[2] = (__bf16)v4[2]; p[3] = (__bf16)v4[3];
            const int unit = ((row >> 4) * 128) + (kh * 64) + (kgv * 16) + (row & 15);
            *(bf16x4*)(vfE + unit * 8 + e0) = p;
        }
    }

    // ---- stage K/V feature planes (vectorized) + SV partials ----
    {
        const int dl4 = t & 7;             // 4-d group: d-local = dl4*4 + jd
        const int sgg = t >> 3;            // 0..63 (8-s fragment octet)
        const int ksb = sgg >> 2, kgb = sgg & 3;
        const size_t gbase = (((size_t)n * S + sgg * 8) * H + h) * D + dt * 32 + dl4 * 4;
        const size_t sstep = (size_t)H * D;

        f32x4 K4[8], V4[8];
        #pragma unroll
        for (int j = 0; j < 8; ++j) {
            K4[j] = *(const f32x4*)(keys + gbase + j * sstep);
            V4[j] = *(const f32x4*)(values + gbase + j * sstep);
        }
        const f32x4 kla = *(const f32x4*)(klen + n * S + sgg * 8);
        const f32x4 klb = *(const f32x4*)(klen + n * S + sgg * 8 + 4);
        float kl[8] = {kla[0], kla[1], kla[2], kla[3],
                       klb[0], klb[1], klb[2], klb[3]};

        float sva[4] = {0.f, 0.f, 0.f, 0.f};
        #pragma unroll
        for (int jd = 0; jd < 4; ++jd) {
            bf16x8 nv, dv;
            #pragma unroll
            for (int j = 0; j < 8; ++j) {
                const float kk = K4[j][jd] + kl[j];
                nv[j] = (__bf16)(kk * V4[j][jd]);
                dv[j] = (__bf16)kk;
                sva[jd] += V4[j][jd];
            }
            const int dloc = dl4 * 4 + jd;
            const int cg = dloc >> 4, rb = dloc & 15;
            lB[((0 * 2 + cg) * 16 + ksb) * 64 + kgb * 16 + rb] = nv;
            lB[((1 * 2 + cg) * 16 + ksb) * 64 + kgb * 16 + rb] = dv;
        }
        #pragma unroll
        for (int jd = 0; jd < 4; ++jd) svred[sgg][dl4 * 4 + jd] = sva[jd];
    }

    // ---- early epilogue loads (input-only) ----
    const int dcol = dt * 32 + dh * 16 + r;
    float qv[4];
    size_t qidx[4];
    #pragma unroll
    for (int rr = 0; rr < 4; ++rr) {
        const int l = l0w + kg * 4 + rr;
        qidx[rr] = (((size_t)n * L + l) * H + h) * D + dcol;
        qv[rr] = queries[qidx[rr]];
    }

    // ---- u fragments (w-GEMM A-operand): lane r = l-row, kg = k-octet ----
    const float* urow = u + (size_t)(l0w + r) * K64 + kg * 8;
    const bf16x8 u0 = tobf8(*(const f32x4*)urow, *(const f32x4*)(urow + 4));
    const bf16x8 u1 = tobf8(*(const f32x4*)(urow + 32), *(const f32x4*)(urow + 36));

    __syncthreads();
    if (t < 32) {
        float ssum = 0.f;
        #pragma unroll
        for (int j = 0; j < 64; ++j) ssum += svred[j][t];
        svl[t] = ssum;
    }
    __syncthreads();

    // mask base for this wave's C/D rows (row = kg*4 + reg, col = st*16 + r)
    const float* mbase = mask + (size_t)(l0w + kg * 4) * S + r;
    const int colb = dh * 16 + r;

    f32x4 accn = {0.f, 0.f, 0.f, 0.f};
    f32x4 accd = {0.f, 0.f, 0.f, 0.f};

    // mask regs for the NEXT produce (ks_p = 0 initially)
    float mk[4];
    #pragma unroll
    for (int reg = 0; reg < 4; ++reg)
        mk[reg] = mbase[(size_t)reg * S + dh * 16];

    // prologue: produce(0)
    {
        __bf16* const scrW = &wscr[lw][0][0];
        const int st = dh;
        const bf16x8 vf0 = vf[st * 128 + lane];
        const bf16x8 vf1 = vf[st * 128 + 64 + lane];
        f32x4 wacc = {0.f, 0.f, 0.f, 0.f};
        wacc = mfma16(u0, vf0, wacc);
        wacc = mfma16(u1, vf1, wacc);
        #pragma unroll
        for (int reg = 0; reg < 4; ++reg)
            scrW[(kg * 4 + reg) * SCW + colb] = (__bf16)(wacc[reg] + mk[reg]);
    }
    // prefetch mask for produce(1)
    #pragma unroll
    for (int reg = 0; reg < 4; ++reg)
        mk[reg] = mbase[(size_t)reg * S + (2 + dh) * 16];
    __syncthreads();

    #pragma unroll 2
    for (int ks = 0; ks < 16; ++ks) {
        // consume(ks): issue LDS reads first (in-order DS queue, not behind writes)
        __bf16* const scrR = &wscr[lw][ks & 1][0];
        const bf16x8 a  = *(const bf16x8*)(scrR + r * SCW + kg * 8);
        const bf16x8 bn = lB[((0 * 2 + dh) * 16 + ks) * 64 + lane];
        const bf16x8 bd = lB[((1 * 2 + dh) * 16 + ks) * 64 + lane];

        if (ks < 15) {
            // produce(ks+1) — mask already in registers, no VMEM wait here
            __bf16* const scrW = &wscr[lw][(ks + 1) & 1][0];
            const int st = (ks + 1) * 2 + dh;
            const bf16x8 vf0 = vf[st * 128 + lane];
            const bf16x8 vf1 = vf[st * 128 + 64 + lane];
            f32x4 wacc = {0.f, 0.f, 0.f, 0.f};
            wacc = mfma16(u0, vf0, wacc);
            wacc = mfma16(u1, vf1, wacc);
            #pragma unroll
            for (int reg = 0; reg < 4; ++reg)
                scrW[(kg * 4 + reg) * SCW + colb] = (__bf16)(wacc[reg] + mk[reg]);
            if (ks < 14) {
                const int stn = (ks + 2) * 2 + dh;
                #pragma unroll
                for (int reg = 0; reg < 4; ++reg)
                    mk[reg] = mbase[(size_t)reg * S + stn * 16];
            }
        }

        accn = mfma16(a, bn, accn);
        accd = mfma16(a, bd, accd);
        __syncthreads();
    }

    const float sv = svl[dh * 16 + r];
    #pragma unroll
    for (int rr = 0; rr < 4; ++rr) {
        const float sig =
            __builtin_amdgcn_rcpf(1.0f + __builtin_amdgcn_exp2f(-qv[rr] * LOG2E));
        const float numv = sv + accn[rr];
        const float denv = 512.0f + accd[rr];
        out[qidx[rr]] = sig * numv * __builtin_amdgcn_rcpf(denv);
    }
}
} // namespace

extern "C" void kernel_launch(void* const* d_in, const int* in_sizes, int n_in,
                              void* d_out, int out_size, void* d_ws, size_t ws_size,
                              hipStream_t stream)
{
    const float* queries = (const float*)d_in[0];
    const float* keys    = (const float*)d_in[1];
    const float* values  = (const float*)d_in[2];
    const float* mask    = (const float*)d_in[3];
    const float* klen    = (const float*)d_in[4];
    const float* u       = (const float*)d_in[5];
    const float* v       = (const float*)d_in[6];
    float* out = (float*)d_out;

    aft_once<<<dim3(256), dim3(512), 0, stream>>>(
        u, v, mask, keys, values, klen, queries, out);
}

// Round 24
// 14.400 us; speedup vs baseline: 1.2725x; 1.0542x over previous
//
#include <hip/hip_runtime.h>
#include <math.h>

namespace {
constexpr int L = 512, S = 512, H = 8, D = 64, K64 = 64;
constexpr float LOG2E = 1.4426950408889634f;
constexpr int SCW = 40;              // w-scratch stride (elems): 80 B -> 16B-aligned b128 reads

typedef __bf16 bf16x8 __attribute__((ext_vector_type(8)));
typedef __bf16 bf16x4 __attribute__((ext_vector_type(4)));
typedef float  f32x4  __attribute__((ext_vector_type(4)));

__device__ inline f32x4 mfma16(bf16x8 a, bf16x8 b, f32x4 c) {
    return __builtin_amdgcn_mfma_f32_16x16x32_bf16(a, b, c, 0, 0, 0);
}
__device__ inline bf16x8 tobf8(f32x4 a, f32x4 b) {
    bf16x8 r;
    r[0] = (__bf16)a[0]; r[1] = (__bf16)a[1];
    r[2] = (__bf16)a[2]; r[3] = (__bf16)a[3];
    r[4] = (__bf16)b[0]; r[5] = (__bf16)b[1];
    r[6] = (__bf16)b[2]; r[7] = (__bf16)b[3];
    return r;
}

// Single dispatch. grid 256 = XCD-swizzled nh(16) x mt(8) x dt(2); 512 thr = 8 waves.
// Wave wv: lw = wv&3 -> 16 l-rows; dh = wv>>2 -> 16 d-cols; the (lw,0/1) pair
// splits w-production (each wave produces st = 2ks+dh).
// NEW vs R23: TWO ks per barrier phase via a 4-deep scratch ring wscr[lw][4].
// Phase k2: consume(2k2, 2k2+1) from slots {2k2&3, 2k2+1&3}; produce
// (2k2+2, 2k2+3) into the disjoint pair; 4 main MFMAs clustered; ONE barrier.
// Mask values register-prefetched two tiles ahead (produce path VMEM-free).
__global__ __launch_bounds__(512, 1) void aft_once(
    const float* __restrict__ u, const float* __restrict__ v,
    const float* __restrict__ mask, const float* __restrict__ keys,
    const float* __restrict__ values, const float* __restrict__ klen,
    const float* __restrict__ queries, float* __restrict__ out)
{
    __shared__ bf16x8 vf[4096];           // 64 KB
    __shared__ bf16x8 lB[4096];           // 64 KB
    __shared__ __bf16 wscr[4][4][16 * SCW];  // 20 KB  per-lw 4-slot ring
    __shared__ float  svred[64][33];      // 8.25 KB  [sgg][d-local]
    __shared__ float  svl[32];

    const int b = blockIdx.x;
    const int xcd = b & 7;
    const int i = b >> 3;                  // 0..31
    const int nh = xcd + ((i >> 4) << 3);  // {xcd, xcd+8}
    const int rem = i & 15;
    const int mt = rem >> 1;               // 0..7 (64 l-rows)
    const int dt = rem & 1;                // 0..1 (32 d-cols)
    const int n = nh >> 3, h = nh & 7;

    const int t = threadIdx.x;
    const int wv = t >> 6;
    const int lane = t & 63;
    const int r = lane & 15;
    const int kg = lane >> 4;
    const int lw = wv & 3;
    const int dh = wv >> 2;
    const int l0w = mt * 64 + lw * 16;

    // ---- stage v -> LDS fragments (coalesced rows; unit = st*128+kh*64+kg*16+r) ----
    {
        const int rq = t >> 4;             // 0..31
        const int c4 = (t & 15) << 2;      // 0..60
        const int kh = c4 >> 5, kgv = (c4 >> 3) & 3, e0 = c4 & 7;
        __bf16* vfE = (__bf16*)vf;
        #pragma unroll
        for (int rd = 0; rd < 16; ++rd) {
            const int row = rq + rd * 32;
            const f32x4 v4 = *(const f32x4*)(v + (size_t)row * K64 + c4);
            bf16x4 p;
            p[0] = (__bf16)v4[0]; p[1] = (__bf16)v4[1];
            p[2] = (__bf16)v4[2]; p[3] = (__bf16)v4[3];
            const int unit = ((row >> 4) * 128) + (kh * 64) + (kgv * 16) + (row & 15);
            *(bf16x4*)(vfE + unit * 8 + e0) = p;
        }
    }

    // ---- stage K/V feature planes (vectorized) + SV partials ----
    {
        const int dl4 = t & 7;             // 4-d group: d-local = dl4*4 + jd
        const int sgg = t >> 3;            // 0..63 (8-s fragment octet)
        const int ksb = sgg >> 2, kgb = sgg & 3;
        const size_t gbase = (((size_t)n * S + sgg * 8) * H + h) * D + dt * 32 + dl4 * 4;
        const size_t sstep = (size_t)H * D;

        f32x4 K4[8], V4[8];
        #pragma unroll
        for (int j = 0; j < 8; ++j) {
            K4[j] = *(const f32x4*)(keys + gbase + j * sstep);
            V4[j] = *(const f32x4*)(values + gbase + j * sstep);
        }
        const f32x4 kla = *(const f32x4*)(klen + n * S + sgg * 8);
        const f32x4 klb = *(const f32x4*)(klen + n * S + sgg * 8 + 4);
        float kl[8] = {kla[0], kla[1], kla[2], kla[3],
                       klb[0], klb[1], klb[2], klb[3]};

        float sva[4] = {0.f, 0.f, 0.f, 0.f};
        #pragma unroll
        for (int jd = 0; jd < 4; ++jd) {
            bf16x8 nv, dv;
            #pragma unroll
            for (int j = 0; j < 8; ++j) {
                const float kk = K4[j][jd] + kl[j];
                nv[j] = (__bf16)(kk * V4[j][jd]);
                dv[j] = (__bf16)kk;
                sva[jd] += V4[j][jd];
            }
            const int dloc = dl4 * 4 + jd;
            const int cg = dloc >> 4, rb = dloc & 15;
            lB[((0 * 2 + cg) * 16 + ksb) * 64 + kgb * 16 + rb] = nv;
            lB[((1 * 2 + cg) * 16 + ksb) * 64 + kgb * 16 + rb] = dv;
        }
        #pragma unroll
        for (int jd = 0; jd < 4; ++jd) svred[sgg][dl4 * 4 + jd] = sva[jd];
    }

    // ---- early epilogue loads (input-only) ----
    const int dcol = dt * 32 + dh * 16 + r;
    float qv[4];
    size_t qidx[4];
    #pragma unroll
    for (int rr = 0; rr < 4; ++rr) {
        const int l = l0w + kg * 4 + rr;
        qidx[rr] = (((size_t)n * L + l) * H + h) * D + dcol;
        qv[rr] = queries[qidx[rr]];
    }

    // ---- u fragments (w-GEMM A-operand): lane r = l-row, kg = k-octet ----
    const float* urow = u + (size_t)(l0w + r) * K64 + kg * 8;
    const bf16x8 u0 = tobf8(*(const f32x4*)urow, *(const f32x4*)(urow + 4));
    const bf16x8 u1 = tobf8(*(const f32x4*)(urow + 32), *(const f32x4*)(urow + 36));

    __syncthreads();
    if (t < 32) {
        float ssum = 0.f;
        #pragma unroll
        for (int j = 0; j < 64; ++j) ssum += svred[j][t];
        svl[t] = ssum;
    }
    __syncthreads();

    // mask base for this wave's C/D rows (row = kg*4 + reg, col = st*16 + r)
    const float* mbase = mask + (size_t)(l0w + kg * 4) * S + r;
    const int colb = dh * 16 + r;

    f32x4 accn = {0.f, 0.f, 0.f, 0.f};
    f32x4 accd = {0.f, 0.f, 0.f, 0.f};

    // mask regs for the next TWO produces (ks = 0, 1)
    float mk0[4], mk1[4];
    #pragma unroll
    for (int reg = 0; reg < 4; ++reg) {
        mk0[reg] = mbase[(size_t)reg * S + (0 * 2 + dh) * 16];
        mk1[reg] = mbase[(size_t)reg * S + (1 * 2 + dh) * 16];
    }

    // prologue: produce(0) and produce(1)
    #pragma unroll
    for (int p = 0; p < 2; ++p) {
        __bf16* const scrW = &wscr[lw][p][0];
        const int st = p * 2 + dh;
        const bf16x8 vf0 = vf[st * 128 + lane];
        const bf16x8 vf1 = vf[st * 128 + 64 + lane];
        f32x4 wacc = {0.f, 0.f, 0.f, 0.f};
        wacc = mfma16(u0, vf0, wacc);
        wacc = mfma16(u1, vf1, wacc);
        const float* mk = p ? mk1 : mk0;
        #pragma unroll
        for (int reg = 0; reg < 4; ++reg)
            scrW[(kg * 4 + reg) * SCW + colb] = (__bf16)(wacc[reg] + mk[reg]);
    }
    // prefetch mask for produces (2, 3)
    #pragma unroll
    for (int reg = 0; reg < 4; ++reg) {
        mk0[reg] = mbase[(size_t)reg * S + (2 * 2 + dh) * 16];
        mk1[reg] = mbase[(size_t)reg * S + (3 * 2 + dh) * 16];
    }
    __syncthreads();

    #pragma unroll 2
    for (int k2 = 0; k2 < 8; ++k2) {
        const int ks0 = 2 * k2, ks1 = 2 * k2 + 1;
        // consume reads first (in-order DS queue, not behind produce writes)
        const bf16x8 a0  = *(const bf16x8*)(&wscr[lw][ks0 & 3][0] + r * SCW + kg * 8);
        const bf16x8 a1  = *(const bf16x8*)(&wscr[lw][ks1 & 3][0] + r * SCW + kg * 8);
        const bf16x8 bn0 = lB[((0 * 2 + dh) * 16 + ks0) * 64 + lane];
        const bf16x8 bd0 = lB[((1 * 2 + dh) * 16 + ks0) * 64 + lane];
        const bf16x8 bn1 = lB[((0 * 2 + dh) * 16 + ks1) * 64 + lane];
        const bf16x8 bd1 = lB[((1 * 2 + dh) * 16 + ks1) * 64 + lane];

        if (k2 < 7) {
            // produce(2k2+2) and produce(2k2+3) — mask already in registers
            #pragma unroll
            for (int p = 0; p < 2; ++p) {
                const int ksp = 2 * k2 + 2 + p;
                __bf16* const scrW = &wscr[lw][ksp & 3][0];
                const int st = ksp * 2 + dh;
                const bf16x8 vf0 = vf[st * 128 + lane];
                const bf16x8 vf1 = vf[st * 128 + 64 + lane];
                f32x4 wacc = {0.f, 0.f, 0.f, 0.f};
                wacc = mfma16(u0, vf0, wacc);
                wacc = mfma16(u1, vf1, wacc);
                const float* mk = p ? mk1 : mk0;
                #pragma unroll
                for (int reg = 0; reg < 4; ++reg)
                    scrW[(kg * 4 + reg) * SCW + colb] = (__bf16)(wacc[reg] + mk[reg]);
            }
            if (k2 < 6) {
                #pragma unroll
                for (int reg = 0; reg < 4; ++reg) {
                    mk0[reg] = mbase[(size_t)reg * S + ((2 * k2 + 4) * 2 + dh) * 16];
                    mk1[reg] = mbase[(size_t)reg * S + ((2 * k2 + 5) * 2 + dh) * 16];
                }
            }
        }

        // 4 main MFMAs clustered
        accn = mfma16(a0, bn0, accn);
        accd = mfma16(a0, bd0, accd);
        accn = mfma16(a1, bn1, accn);
        accd = mfma16(a1, bd1, accd);
        __syncthreads();
    }

    const float sv = svl[dh * 16 + r];
    #pragma unroll
    for (int rr = 0; rr < 4; ++rr) {
        const float sig =
            __builtin_amdgcn_rcpf(1.0f + __builtin_amdgcn_exp2f(-qv[rr] * LOG2E));
        const float numv = sv + accn[rr];
        const float denv = 512.0f + accd[rr];
        out[qidx[rr]] = sig * numv * __builtin_amdgcn_rcpf(denv);
    }
}
} // namespace

extern "C" void kernel_launch(void* const* d_in, const int* in_sizes, int n_in,
                              void* d_out, int out_size, void* d_ws, size_t ws_size,
                              hipStream_t stream)
{
    const float* queries = (const float*)d_in[0];
    const float* keys    = (const float*)d_in[1];
    const float* values  = (const float*)d_in[2];
    const float* mask    = (const float*)d_in[3];
    const float* klen    = (const float*)d_in[4];
    const float* u       = (const float*)d_in[5];
    const float* v       = (const float*)d_in[6];
    float* out = (float*)d_out;

    aft_once<<<dim3(256), dim3(512), 0, stream>>>(
        u, v, mask, keys, values, klen, queries, out);
}